// Round 7
// baseline (974.472 us; speedup 1.0000x reference)
//
#include <hip/hip_runtime.h>
#include <stdint.h>

// fused: out = l2norm(relu(x@W1+b1) @ W2 + b2)
// x:[N,64] f32, W1:[64,64], b1:[64], W2:[64,128], b2:[128], out:[N,128] f32
//
// Swapped-operand MFMA design: A = W^T fragment, B = x/h fragment, so
// D[col=lane&15 -> sample][row=4*lq+r -> output dim]. Each lane owns 4
// CONSECUTIVE output dims per acc reg-quad -> dwordx4 stores, 2-shfl L2 reduce.

typedef __attribute__((ext_vector_type(8))) short short8;   // 8 bf16 (MFMA A/B frag)
typedef __attribute__((ext_vector_type(4))) float f32x4;    // MFMA C/D frag

__device__ __forceinline__ ushort f2bf(float f) {
    union { float f; uint32_t u; } v; v.f = f;
    uint32_t u = v.u;
    u += 0x7fffu + ((u >> 16) & 1u);   // round-to-nearest-even
    return (ushort)(u >> 16);
}
__device__ __forceinline__ uint32_t pack2(float a, float b) {
    return (uint32_t)f2bf(a) | ((uint32_t)f2bf(b) << 16);
}

__global__ __launch_bounds__(256, 4)   // force <=128 VGPR -> 4 waves/SIMD
void fused_head_kernel(const float* __restrict__ x,
                       const float* __restrict__ W1,
                       const float* __restrict__ b1,
                       const float* __restrict__ W2,
                       const float* __restrict__ b2,
                       float* __restrict__ out,
                       int ntiles)
{
    // stride 72 ushorts = 144 B = 9*16B: rows 16B-aligned, uniform bank spread
    __shared__ ushort w1t[64][72];      // w1t[n][k] = W1[k][n]
    __shared__ ushort w2t[128][72];     // w2t[n][k] = W2[k][n]
    __shared__ ushort htile[4][16][72]; // per-wave: htile[w][sample][k]
    __shared__ __align__(16) float b1s[64];
    __shared__ __align__(16) float b2s[128];

    const int tid  = threadIdx.x;
    const int wave = tid >> 6;
    const int lane = tid & 63;
    const int l16  = lane & 15;   // sample within wave-tile
    const int lq   = lane >> 4;   // 0..3

    int tile = blockIdx.x;

    // issue first tile's x loads BEFORE weight staging (latency hides under it)
    f32x4 uA[4], uB[4];
    {
        const float* p = x + ((size_t)(tile * 64 + wave * 16 + l16)) * 64 + lq * 8;
        uA[0] = *(const f32x4*)p;        uA[1] = *(const f32x4*)(p + 4);
        uA[2] = *(const f32x4*)(p + 32); uA[3] = *(const f32x4*)(p + 36);
    }

    // ---- stage weights + biases (once per block) ----
    for (int idx = tid; idx < 64 * 64; idx += 256) {
        int k = idx >> 6, n = idx & 63;
        w1t[n][k] = f2bf(W1[idx]);
    }
    for (int idx = tid; idx < 64 * 128; idx += 256) {
        int k = idx >> 7, n = idx & 127;
        w2t[n][k] = f2bf(W2[idx]);
    }
    if (tid < 64)  b1s[tid] = b1[tid];
    if (tid < 128) b2s[tid] = b2[tid];
    __syncthreads();

    auto loadx = [&](f32x4* u, int t) {
        const float* p = x + ((size_t)(t * 64 + wave * 16 + l16)) * 64 + lq * 8;
        u[0] = *(const f32x4*)p;        u[1] = *(const f32x4*)(p + 4);
        u[2] = *(const f32x4*)(p + 32); u[3] = *(const f32x4*)(p + 36);
    };

    auto process = [&](const f32x4* u, int t) {
        // B-frag for stage 1: x[sample=l16][k=32h+8lq+e]
        short8 xf[2];
#pragma unroll
        for (int h = 0; h < 2; ++h) {
            short8 v;
            v[0] = (short)f2bf(u[2*h][0]);   v[1] = (short)f2bf(u[2*h][1]);
            v[2] = (short)f2bf(u[2*h][2]);   v[3] = (short)f2bf(u[2*h][3]);
            v[4] = (short)f2bf(u[2*h+1][0]); v[5] = (short)f2bf(u[2*h+1][1]);
            v[6] = (short)f2bf(u[2*h+1][2]); v[7] = (short)f2bf(u[2*h+1][3]);
            xf[h] = v;
        }

        // ---- stage 1: D[dim][sample] = W1^T x ; acc1[nt][r] = h_pre[l16][16nt+4lq+r]
        f32x4 acc1[4] = {};
#pragma unroll
        for (int h = 0; h < 2; ++h)
#pragma unroll
            for (int nt = 0; nt < 4; ++nt) {
                short8 wf = *(const short8*)&w1t[nt * 16 + l16][h * 32 + lq * 8];
                acc1[nt] = __builtin_amdgcn_mfma_f32_16x16x32_bf16(wf, xf[h], acc1[nt], 0, 0, 0);
            }

        // bias+relu -> htile[wave][own sample row l16][dim] as packed bf16 pairs
#pragma unroll
        for (int nt = 0; nt < 4; ++nt) {
            f32x4 bv = *(const f32x4*)&b1s[nt * 16 + lq * 4];
            float h0 = acc1[nt][0] + bv[0]; h0 = h0 > 0.f ? h0 : 0.f;
            float h1 = acc1[nt][1] + bv[1]; h1 = h1 > 0.f ? h1 : 0.f;
            float h2 = acc1[nt][2] + bv[2]; h2 = h2 > 0.f ? h2 : 0.f;
            float h3 = acc1[nt][3] + bv[3]; h3 = h3 > 0.f ? h3 : 0.f;
            uint32_t* dst = (uint32_t*)&htile[wave][l16][nt * 16 + lq * 4];
            dst[0] = pack2(h0, h1);
            dst[1] = pack2(h2, h3);
        }
        // wave-private buffer, in-order LDS per wave: no barrier needed

        // ---- stage 2: D[dim][sample] = W2^T h ; acc2[nt][r] = e[l16][16nt+4lq+r]
        f32x4 acc2[8] = {};
#pragma unroll
        for (int h = 0; h < 2; ++h) {
            short8 hf = *(const short8*)&htile[wave][l16][h * 32 + lq * 8];
#pragma unroll
            for (int nt = 0; nt < 8; ++nt) {
                short8 wf = *(const short8*)&w2t[nt * 16 + l16][h * 32 + lq * 8];
                acc2[nt] = __builtin_amdgcn_mfma_f32_16x16x32_bf16(wf, hf, acc2[nt], 0, 0, 0);
            }
        }

        // ---- bias + sum of squares: lane holds 32 dims of sample l16
        float ss = 0.f;
#pragma unroll
        for (int nt = 0; nt < 8; ++nt) {
            f32x4 bv = *(const f32x4*)&b2s[nt * 16 + lq * 4];
#pragma unroll
            for (int r = 0; r < 4; ++r) {
                float e = acc2[nt][r] + bv[r];
                acc2[nt][r] = e;
                ss += e * e;
            }
        }
        // combine the 4 lq-groups holding sample l16 (lanes l16+16*lq)
        ss += __shfl_xor(ss, 16, 64);
        ss += __shfl_xor(ss, 32, 64);
        float sc = ss > 0.f ? rsqrtf(ss) : 0.f;   // zero-norm guard

        // ---- coalesced dwordx4 stores: 8 instrs x 1KB/wave
        float* po = out + ((size_t)(t * 64 + wave * 16 + l16)) * 128 + lq * 4;
#pragma unroll
        for (int nt = 0; nt < 8; ++nt) {
            f32x4 v;
            v[0] = acc2[nt][0] * sc; v[1] = acc2[nt][1] * sc;
            v[2] = acc2[nt][2] * sc; v[3] = acc2[nt][3] * sc;
            *(f32x4*)(po + nt * 16) = v;
        }
    };

    // ---- ping-pong pipelined tile loop: issue t+1's loads before computing t
    int next = tile + gridDim.x;
    while (true) {
        bool hasB = next < ntiles;
        if (hasB) loadx(uB, next);
        process(uA, tile);
        if (!hasB) break;
        tile = next; next += gridDim.x;
        bool hasA = next < ntiles;
        if (hasA) loadx(uA, next);
        process(uB, tile);
        if (!hasA) break;
        tile = next; next += gridDim.x;
    }
}

extern "C" void kernel_launch(void* const* d_in, const int* in_sizes, int n_in,
                              void* d_out, int out_size, void* d_ws, size_t ws_size,
                              hipStream_t stream) {
    const float* x  = (const float*)d_in[0];
    const float* W1 = (const float*)d_in[1];
    const float* b1 = (const float*)d_in[2];
    const float* W2 = (const float*)d_in[3];
    const float* b2 = (const float*)d_in[4];
    float* out = (float*)d_out;

    const int nrows  = in_sizes[0] / 64;   // 1,000,000
    const int ntiles = nrows / 64;         // 15625 (exact)
    int grid = ntiles < 3125 ? ntiles : 3125;  // 5 tiles/block

    hipLaunchKernelGGL(fused_head_kernel, dim3(grid), dim3(256), 0, stream,
                       x, W1, b1, W2, b2, out, ntiles);
}

// Round 9
// 700.529 us; speedup vs baseline: 1.3911x; 1.3911x over previous
//
#include <hip/hip_runtime.h>
#include <stdint.h>

// fused: out = l2norm(relu(x@W1+b1) @ W2 + b2)
// x:[N,64] f32, W1:[64,64], b1:[64], W2:[64,128], b2:[128], out:[N,128] f32
//
// Swapped-operand MFMA design: A = W^T fragment, B = x/h fragment, so
// D[col=lane&15 -> sample][row=4*lq+r -> output dim]. Each lane owns 4
// CONSECUTIVE output dims per acc reg-quad -> dwordx4 stores, 2-shfl L2 reduce.
//
// R7 lesson: __launch_bounds__(256,4) clamped VGPRs to 64 -> scratch spills
// (+900 MB HBM traffic, 500us). Bound relaxed to (256): ~100 live regs fit
// in 128, occupancy becomes LDS-limited (37.9KB -> 4 blocks/CU, 16 waves).

typedef __attribute__((ext_vector_type(8))) short short8;   // 8 bf16 (MFMA A/B frag)
typedef __attribute__((ext_vector_type(4))) float f32x4;    // MFMA C/D frag

__device__ __forceinline__ ushort f2bf(float f) {
    union { float f; uint32_t u; } v; v.f = f;
    uint32_t u = v.u;
    u += 0x7fffu + ((u >> 16) & 1u);   // round-to-nearest-even
    return (ushort)(u >> 16);
}
__device__ __forceinline__ uint32_t pack2(float a, float b) {
    return (uint32_t)f2bf(a) | ((uint32_t)f2bf(b) << 16);
}

__global__ __launch_bounds__(256)   // NO min-waves clamp (R7: it forced 64 VGPR -> spills)
void fused_head_kernel(const float* __restrict__ x,
                       const float* __restrict__ W1,
                       const float* __restrict__ b1,
                       const float* __restrict__ W2,
                       const float* __restrict__ b2,
                       float* __restrict__ out,
                       int ntiles)
{
    // stride 72 ushorts = 144 B = 9*16B: rows 16B-aligned, uniform bank spread
    __shared__ ushort w1t[64][72];      // w1t[n][k] = W1[k][n]
    __shared__ ushort w2t[128][72];     // w2t[n][k] = W2[k][n]
    __shared__ ushort htile[4][16][72]; // per-wave: htile[w][sample][k]
    __shared__ __align__(16) float b1s[64];
    __shared__ __align__(16) float b2s[128];

    const int tid  = threadIdx.x;
    const int wave = tid >> 6;
    const int lane = tid & 63;
    const int l16  = lane & 15;   // sample within wave-tile
    const int lq   = lane >> 4;   // 0..3

    int tile = blockIdx.x;

    // issue first tile's x loads BEFORE weight staging (latency hides under it)
    f32x4 uA[4], uB[4];
    {
        const float* p = x + ((size_t)(tile * 64 + wave * 16 + l16)) * 64 + lq * 8;
        uA[0] = *(const f32x4*)p;        uA[1] = *(const f32x4*)(p + 4);
        uA[2] = *(const f32x4*)(p + 32); uA[3] = *(const f32x4*)(p + 36);
    }

    // ---- stage weights + biases (once per block) ----
    for (int idx = tid; idx < 64 * 64; idx += 256) {
        int k = idx >> 6, n = idx & 63;
        w1t[n][k] = f2bf(W1[idx]);
    }
    for (int idx = tid; idx < 64 * 128; idx += 256) {
        int k = idx >> 7, n = idx & 127;
        w2t[n][k] = f2bf(W2[idx]);
    }
    if (tid < 64)  b1s[tid] = b1[tid];
    if (tid < 128) b2s[tid] = b2[tid];
    __syncthreads();

    auto loadx = [&](f32x4* u, int t) {
        const float* p = x + ((size_t)(t * 64 + wave * 16 + l16)) * 64 + lq * 8;
        u[0] = *(const f32x4*)p;        u[1] = *(const f32x4*)(p + 4);
        u[2] = *(const f32x4*)(p + 32); u[3] = *(const f32x4*)(p + 36);
    };

    auto process = [&](const f32x4* u, int t) {
        // B-frag for stage 1: x[sample=l16][k=32h+8lq+e]
        short8 xf[2];
#pragma unroll
        for (int h = 0; h < 2; ++h) {
            short8 v;
            v[0] = (short)f2bf(u[2*h][0]);   v[1] = (short)f2bf(u[2*h][1]);
            v[2] = (short)f2bf(u[2*h][2]);   v[3] = (short)f2bf(u[2*h][3]);
            v[4] = (short)f2bf(u[2*h+1][0]); v[5] = (short)f2bf(u[2*h+1][1]);
            v[6] = (short)f2bf(u[2*h+1][2]); v[7] = (short)f2bf(u[2*h+1][3]);
            xf[h] = v;
        }

        // ---- stage 1: D[dim][sample] = W1^T x ; acc1[nt][r] = h_pre[l16][16nt+4lq+r]
        f32x4 acc1[4] = {};
#pragma unroll
        for (int h = 0; h < 2; ++h)
#pragma unroll
            for (int nt = 0; nt < 4; ++nt) {
                short8 wf = *(const short8*)&w1t[nt * 16 + l16][h * 32 + lq * 8];
                acc1[nt] = __builtin_amdgcn_mfma_f32_16x16x32_bf16(wf, xf[h], acc1[nt], 0, 0, 0);
            }

        // bias+relu -> htile[wave][own sample row l16][dim] as packed bf16 pairs
#pragma unroll
        for (int nt = 0; nt < 4; ++nt) {
            f32x4 bv = *(const f32x4*)&b1s[nt * 16 + lq * 4];
            float h0 = acc1[nt][0] + bv[0]; h0 = h0 > 0.f ? h0 : 0.f;
            float h1 = acc1[nt][1] + bv[1]; h1 = h1 > 0.f ? h1 : 0.f;
            float h2 = acc1[nt][2] + bv[2]; h2 = h2 > 0.f ? h2 : 0.f;
            float h3 = acc1[nt][3] + bv[3]; h3 = h3 > 0.f ? h3 : 0.f;
            uint32_t* dst = (uint32_t*)&htile[wave][l16][nt * 16 + lq * 4];
            dst[0] = pack2(h0, h1);
            dst[1] = pack2(h2, h3);
        }
        // wave-private buffer, in-order LDS per wave: no barrier needed

        // ---- stage 2: D[dim][sample] = W2^T h ; acc2[nt][r] = e[l16][16nt+4lq+r]
        f32x4 acc2[8] = {};
#pragma unroll
        for (int h = 0; h < 2; ++h) {
            short8 hf = *(const short8*)&htile[wave][l16][h * 32 + lq * 8];
#pragma unroll
            for (int nt = 0; nt < 8; ++nt) {
                short8 wf = *(const short8*)&w2t[nt * 16 + l16][h * 32 + lq * 8];
                acc2[nt] = __builtin_amdgcn_mfma_f32_16x16x32_bf16(wf, hf, acc2[nt], 0, 0, 0);
            }
        }

        // ---- bias + sum of squares: lane holds 32 dims of sample l16
        float ss = 0.f;
#pragma unroll
        for (int nt = 0; nt < 8; ++nt) {
            f32x4 bv = *(const f32x4*)&b2s[nt * 16 + lq * 4];
#pragma unroll
            for (int r = 0; r < 4; ++r) {
                float e = acc2[nt][r] + bv[r];
                acc2[nt][r] = e;
                ss += e * e;
            }
        }
        // combine the 4 lq-groups holding sample l16 (lanes l16+16*lq)
        ss += __shfl_xor(ss, 16, 64);
        ss += __shfl_xor(ss, 32, 64);
        float sc = ss > 0.f ? rsqrtf(ss) : 0.f;   // zero-norm guard

        // ---- coalesced dwordx4 stores: 8 instrs x 1KB/wave
        float* po = out + ((size_t)(t * 64 + wave * 16 + l16)) * 128 + lq * 4;
#pragma unroll
        for (int nt = 0; nt < 8; ++nt) {
            f32x4 v;
            v[0] = acc2[nt][0] * sc; v[1] = acc2[nt][1] * sc;
            v[2] = acc2[nt][2] * sc; v[3] = acc2[nt][3] * sc;
            *(f32x4*)(po + nt * 16) = v;
        }
    };

    // ---- ping-pong pipelined tile loop: issue t+1's loads before computing t
    int next = tile + gridDim.x;
    while (true) {
        bool hasB = next < ntiles;
        if (hasB) loadx(uB, next);
        process(uA, tile);
        if (!hasB) break;
        tile = next; next += gridDim.x;
        bool hasA = next < ntiles;
        if (hasA) loadx(uA, next);
        process(uB, tile);
        if (!hasA) break;
        tile = next; next += gridDim.x;
    }
}

extern "C" void kernel_launch(void* const* d_in, const int* in_sizes, int n_in,
                              void* d_out, int out_size, void* d_ws, size_t ws_size,
                              hipStream_t stream) {
    const float* x  = (const float*)d_in[0];
    const float* W1 = (const float*)d_in[1];
    const float* b1 = (const float*)d_in[2];
    const float* W2 = (const float*)d_in[3];
    const float* b2 = (const float*)d_in[4];
    float* out = (float*)d_out;

    const int nrows  = in_sizes[0] / 64;   // 1,000,000
    const int ntiles = nrows / 64;         // 15625 (exact)
    int grid = ntiles < 3125 ? ntiles : 3125;  // 5 tiles/block

    hipLaunchKernelGGL(fused_head_kernel, dim3(grid), dim3(256), 0, stream,
                       x, W1, b1, W2, b2, out, ntiles);
}